// Round 3
// baseline (293.024 us; speedup 1.0000x reference)
//
#include <hip/hip_runtime.h>
#include <hip/hip_bf16.h>
#include <cstdint>

#define NHEADS 8
#define NPOINTS 4

typedef __bf16 bf16x8 __attribute__((ext_vector_type(8)));
typedef float f32x4 __attribute__((ext_vector_type(4)));

__device__ __forceinline__ ushort f2bf_rn(float x) {
  union { float f; uint32_t u; } c; c.f = x;
  uint32_t r = c.u + 0x7fffu + ((c.u >> 16) & 1u);
  return (ushort)(r >> 16);
}
__device__ __forceinline__ float bf2f(ushort h) {
  union { uint32_t u; float f; } c; c.u = ((uint32_t)h) << 16; return c.f;
}

// XOR-swizzled LDS index (ushort units). Tile row = 64 bf16 = 128 B.
// byte ^= (row&7)<<4 spreads the 16B column slots across banks (G4 pattern).
__device__ __forceinline__ int swz_idx(int row, int byte_in_row) {
  return ((row * 128 + byte_in_row) ^ ((row & 7) << 4)) >> 1;
}

// ---------------------------------------------------------------------------
// Split-bf16 (3x MFMA) GEMM with bias: C[M,N] = A[M,K] @ B[K,N] + bias[N]
// A fp32 row-major, converted to hi/lo bf16 in-kernel, staged in LDS (32 KB).
// B pre-split+transposed (BT_hi/BT_lo bf16 [N][K]) read DIRECTLY from global
// per fragment — W is 256 KB, L2-resident, shared by all blocks; no LDS.
// Tile 128x128, BK=64, 256 threads (4 waves 2x2, each 64x64 via 4x4 frags of
// 16x16x32 MFMA). Occupancy target: 4 blocks/CU (VGPR<=128, LDS 32 KB).
// This GEMM is HBM-bound (A read + C write); occupancy is the lever.
// ---------------------------------------------------------------------------
__global__ __launch_bounds__(256, 4) void gemm_split3(
    const float* __restrict__ A,
    const ushort* __restrict__ BT_hi, const ushort* __restrict__ BT_lo,
    const float* __restrict__ bias, float* __restrict__ C,
    int M, int N, int K)
{
  __shared__ ushort Ah[128 * 64], Al[128 * 64];
  const int tid  = threadIdx.x;
  const int lane = tid & 63, wave = tid >> 6;
  const int wm = (wave >> 1) * 64, wn = (wave & 1) * 64;
  const int lrow = lane & 15, lgrp = lane >> 4;
  const long brow = (long)blockIdx.y * 128;
  const int  bcol = blockIdx.x * 128;

  f32x4 acc[4][4] = {};

  for (int k0 = 0; k0 < K; k0 += 64) {
    // ---- global A loads to regs (8 x float4 per thread) ----
    float4 areg[8];
#pragma unroll
    for (int i = 0; i < 8; ++i) {
      const int idx = i * 256 + tid;
      const int r = idx >> 4, c = (idx & 15) << 2;       // 16 float4 per row
      areg[i] = *(const float4*)&A[(size_t)(brow + r) * K + k0 + c];
    }

    __syncthreads();  // previous iteration's LDS reads must be complete

    // ---- convert + LDS writes (swizzled) ----
#pragma unroll
    for (int i = 0; i < 8; ++i) {
      const int idx = i * 256 + tid;
      const int r = idx >> 4, c = (idx & 15) << 2;
      const float v[4] = {areg[i].x, areg[i].y, areg[i].z, areg[i].w};
      ushort hi[4], lo[4];
#pragma unroll
      for (int j = 0; j < 4; ++j) {
        hi[j] = f2bf_rn(v[j]);
        lo[j] = f2bf_rn(v[j] - bf2f(hi[j]));
      }
      const int si = swz_idx(r, c * 2);
      *(ushort4*)&Ah[si] = make_ushort4(hi[0], hi[1], hi[2], hi[3]);
      *(ushort4*)&Al[si] = make_ushort4(lo[0], lo[1], lo[2], lo[3]);
    }

    __syncthreads();

    // ---- per K=32 step: B frags from global (L2), A frags from LDS, MFMA ----
#pragma unroll
    for (int s = 0; s < 2; ++s) {
      bf16x8 ah[4], al[4], bh[4], bl[4];
#pragma unroll
      for (int t = 0; t < 4; ++t) {
        const int col = bcol + wn + t * 16 + lrow;
        const size_t boff = (size_t)col * K + k0 + s * 32 + lgrp * 8;
        bh[t] = *(const bf16x8*)&BT_hi[boff];
        bl[t] = *(const bf16x8*)&BT_lo[boff];
        const int ai = swz_idx(wm + t * 16 + lrow, s * 64 + lgrp * 16);
        ah[t] = *(const bf16x8*)&Ah[ai];
        al[t] = *(const bf16x8*)&Al[ai];
      }
#pragma unroll
      for (int mt = 0; mt < 4; ++mt)
#pragma unroll
        for (int nt = 0; nt < 4; ++nt) {
          acc[mt][nt] = __builtin_amdgcn_mfma_f32_16x16x32_bf16(ah[mt], bh[nt], acc[mt][nt], 0, 0, 0);
          acc[mt][nt] = __builtin_amdgcn_mfma_f32_16x16x32_bf16(ah[mt], bl[nt], acc[mt][nt], 0, 0, 0);
          acc[mt][nt] = __builtin_amdgcn_mfma_f32_16x16x32_bf16(al[mt], bh[nt], acc[mt][nt], 0, 0, 0);
        }
    }
  }

  // ---- epilogue: C/D layout col=lane&15, row=(lane>>4)*4+reg ----
#pragma unroll
  for (int nt = 0; nt < 4; ++nt) {
    const int col = bcol + wn + nt * 16 + lrow;
    const float bb = bias[col];
#pragma unroll
    for (int mt = 0; mt < 4; ++mt) {
      const long row0 = brow + wm + mt * 16 + lgrp * 4;
      const f32x4 v = acc[mt][nt];
#pragma unroll
      for (int j = 0; j < 4; ++j)
        C[(size_t)(row0 + j) * N + col] = v[j] + bb;
    }
  }
}

// ---------------------------------------------------------------------------
// Weight prep: W fp32 [256][256] -> WT_hi/WT_lo bf16 [n][k] (transposed+split)
// ---------------------------------------------------------------------------
__global__ __launch_bounds__(256) void prep_wt(
    const float* __restrict__ W, ushort* __restrict__ WT_hi, ushort* __restrict__ WT_lo)
{
  const int n = blockIdx.x;
  const int k = threadIdx.x;
  const float w = W[k * 256 + n];
  const ushort hi = f2bf_rn(w);
  const ushort lo = f2bf_rn(w - bf2f(hi));
  WT_hi[n * 256 + k] = hi;
  WT_lo[n * 256 + k] = lo;
}

// ---------------------------------------------------------------------------
// Offsets + attention-logits projection (unchanged).
// ---------------------------------------------------------------------------
__global__ __launch_bounds__(128) void proj_kernel(
    const float* __restrict__ query,
    const float* __restrict__ W_off, const float* __restrict__ b_off,
    const float* __restrict__ W_attn, const float* __restrict__ b_attn,
    float* __restrict__ offs, float* __restrict__ logits)
{
  __shared__ float q_lds[8][256];
  const int row0 = blockIdx.x * 8;
  const int tid  = threadIdx.x;

  for (int i = tid; i < 512; i += 128) {
    const int r  = i >> 6;
    const int c4 = (i & 63) << 2;
    *(float4*)&q_lds[r][c4] = *(const float4*)&query[(size_t)(row0 + r) * 256 + c4];
  }
  __syncthreads();
  if (tid >= 96) return;

  float acc[8] = {};
  if (tid < 64) {
    for (int k4 = 0; k4 < 256; k4 += 4) {
      const float w0 = W_off[(k4 + 0) * 64 + tid];
      const float w1 = W_off[(k4 + 1) * 64 + tid];
      const float w2 = W_off[(k4 + 2) * 64 + tid];
      const float w3 = W_off[(k4 + 3) * 64 + tid];
#pragma unroll
      for (int r = 0; r < 8; ++r) {
        float4 q4 = *(const float4*)&q_lds[r][k4];
        acc[r] += q4.x * w0 + q4.y * w1 + q4.z * w2 + q4.w * w3;
      }
    }
    const float bb = b_off[tid];
#pragma unroll
    for (int r = 0; r < 8; ++r)
      offs[(size_t)(row0 + r) * 64 + tid] = acc[r] + bb;
  } else {
    const int j = tid - 64;
    for (int k4 = 0; k4 < 256; k4 += 4) {
      const float w0 = W_attn[(k4 + 0) * 32 + j];
      const float w1 = W_attn[(k4 + 1) * 32 + j];
      const float w2 = W_attn[(k4 + 2) * 32 + j];
      const float w3 = W_attn[(k4 + 3) * 32 + j];
#pragma unroll
      for (int r = 0; r < 8; ++r) {
        float4 q4 = *(const float4*)&q_lds[r][k4];
        acc[r] += q4.x * w0 + q4.y * w1 + q4.z * w2 + q4.w * w3;
      }
    }
    const float bb = b_attn[j];
#pragma unroll
    for (int r = 0; r < 8; ++r)
      logits[(size_t)(row0 + r) * 32 + j] = acc[r] + bb;
  }
}

// ---------------------------------------------------------------------------
// Softmax + bilinear sampling + weighted accumulation (unchanged).
// ---------------------------------------------------------------------------
__global__ __launch_bounds__(256) void sample_kernel(
    const float* __restrict__ refp,
    const float* __restrict__ offs,
    const float* __restrict__ logits,
    const float* __restrict__ values,
    float* __restrict__ mid,
    const int* __restrict__ hptr, const int* __restrict__ wptr,
    int Q, int HW)
{
  const int bq  = blockIdx.x;
  const int b   = bq / Q;
  const int tid = threadIdx.x;

  __shared__ float off_s[64];
  __shared__ float lg_s[32];
  __shared__ float wt_s[32];
  __shared__ float ref_s[2];

  if (tid < 64) {
    off_s[tid] = offs[(size_t)bq * 64 + tid];
  } else if (tid < 96) {
    lg_s[tid - 64] = logits[(size_t)bq * 32 + (tid - 64)];
  } else if (tid == 96) {
    ref_s[0] = refp[(size_t)bq * 2 + 0];
    ref_s[1] = refp[(size_t)bq * 2 + 1];
  }
  __syncthreads();
  if (tid < 8) {
    const float l0 = lg_s[tid * 4 + 0], l1 = lg_s[tid * 4 + 1];
    const float l2 = lg_s[tid * 4 + 2], l3 = lg_s[tid * 4 + 3];
    const float m  = fmaxf(fmaxf(l0, l1), fmaxf(l2, l3));
    const float e0 = expf(l0 - m), e1 = expf(l1 - m);
    const float e2 = expf(l2 - m), e3 = expf(l3 - m);
    const float inv = 1.0f / (e0 + e1 + e2 + e3);
    wt_s[tid * 4 + 0] = e0 * inv;
    wt_s[tid * 4 + 1] = e1 * inv;
    wt_s[tid * 4 + 2] = e2 * inv;
    wt_s[tid * 4 + 3] = e3 * inv;
  }
  __syncthreads();

  const int W_ = *wptr;
  const int H_ = *hptr;
  const int hh = tid >> 5;
  const float rx = ref_s[0], ry = ref_s[1];
  const float* vb = values + (size_t)b * HW * 256;

  float acc = 0.0f;
#pragma unroll
  for (int p = 0; p < NPOINTS; ++p) {
    float lx = rx + off_s[hh * 8 + p * 2 + 0];
    float ly = ry + off_s[hh * 8 + p * 2 + 1];
    lx = fminf(fmaxf(lx, 0.0f), 1.0f);
    ly = fminf(fmaxf(ly, 0.0f), 1.0f);
    const float sx = lx * (float)(W_ - 1);
    const float sy = ly * (float)(H_ - 1);
    int x0 = (int)floorf(sx);
    int y0 = (int)floorf(sy);
    x0 = min(max(x0, 0), W_ - 1);
    y0 = min(max(y0, 0), H_ - 1);
    const int x1 = min(x0 + 1, W_ - 1);
    const int y1 = min(y0 + 1, H_ - 1);
    const float wx1 = sx - (float)x0, wx0 = 1.0f - wx1;
    const float wy1 = sy - (float)y0, wy0 = 1.0f - wy1;

    const float* r0 = vb + (size_t)(y0 * W_) * 256 + tid;
    const float* r1 = vb + (size_t)(y1 * W_) * 256 + tid;
    const float g00 = r0[(size_t)x0 * 256];
    const float g10 = r0[(size_t)x1 * 256];
    const float g01 = r1[(size_t)x0 * 256];
    const float g11 = r1[(size_t)x1 * 256];

    const float bl = g00 * (wx0 * wy0) + g01 * (wx0 * wy1)
                   + g10 * (wx1 * wy0) + g11 * (wx1 * wy1);
    acc += wt_s[hh * 4 + p] * bl;
  }
  mid[(size_t)bq * 256 + tid] = acc;
}

// ---------------------------------------------------------------------------
extern "C" void kernel_launch(void* const* d_in, const int* in_sizes, int n_in,
                              void* d_out, int out_size, void* d_ws, size_t ws_size,
                              hipStream_t stream)
{
  const float* query   = (const float*)d_in[0];
  const float* refp    = (const float*)d_in[1];
  const float* input_f = (const float*)d_in[2];
  const int*   hptr    = (const int*)d_in[3];
  const int*   wptr    = (const int*)d_in[4];
  const float* W_off   = (const float*)d_in[5];
  const float* b_off   = (const float*)d_in[6];
  const float* W_attn  = (const float*)d_in[7];
  const float* b_attn  = (const float*)d_in[8];
  const float* W_val   = (const float*)d_in[9];
  const float* b_val   = (const float*)d_in[10];
  const float* W_out   = (const float*)d_in[11];
  const float* b_out   = (const float*)d_in[12];
  float* out = (float*)d_out;

  const int D   = 256;
  const int BQ  = in_sizes[0] / D;   // 16384
  const int B   = 8;
  const int Q   = BQ / B;            // 2048
  const int BHW = in_sizes[2] / D;   // 80000
  const int HW  = BHW / B;           // 10000

  char* ws = (char*)d_ws;
  float* values = (float*)ws;                                   // 81.92 MB
  size_t o = (size_t)BHW * D * sizeof(float);
  float* offsb  = (float*)(ws + o);  o += (size_t)BQ * 64 * sizeof(float);  // 4.19 MB
  float* logitb = (float*)(ws + o);  o += (size_t)BQ * 32 * sizeof(float);  // 2.10 MB
  float* mid    = (float*)(ws + o);                             // 16.78 MB

  // Overlay split-weight buffers on dead regions:
  //  - WvT (512 KB) at head of `mid` (dead until sample writes mid; WvT dead after gemm1)
  //  - WoT (512 KB) at head of `offs` (offs dead after sample; WoT written after sample)
  ushort* WvT_hi = (ushort*)mid;
  ushort* WvT_lo = WvT_hi + 256 * 256;
  ushort* WoT_hi = (ushort*)offsb;
  ushort* WoT_lo = WoT_hi + 256 * 256;

  // 1. split/transpose W_val, then values = input_flatten @ W_val + b_val
  prep_wt<<<256, 256, 0, stream>>>(W_val, WvT_hi, WvT_lo);
  gemm_split3<<<dim3(D / 128, BHW / 128), 256, 0, stream>>>(
      input_f, WvT_hi, WvT_lo, b_val, values, BHW, D, D);

  // 2. offsets + attention logits
  proj_kernel<<<BQ / 8, 128, 0, stream>>>(
      query, W_off, b_off, W_attn, b_attn, offsb, logitb);

  // 3. softmax + bilinear sampling -> mid
  sample_kernel<<<BQ, 256, 0, stream>>>(
      refp, offsb, logitb, values, mid, hptr, wptr, Q, HW);

  // 4. split/transpose W_out, then out = mid @ W_out + b_out
  prep_wt<<<256, 256, 0, stream>>>(W_out, WoT_hi, WoT_lo);
  gemm_split3<<<dim3(D / 128, BQ / 128), 256, 0, stream>>>(
      mid, WoT_hi, WoT_lo, b_out, out, BQ, D, D);
}

// Round 4
// 238.801 us; speedup vs baseline: 1.2271x; 1.2271x over previous
//
#include <hip/hip_runtime.h>
#include <hip/hip_bf16.h>
#include <cstdint>

#define NHEADS 8
#define NPOINTS 4

typedef __bf16 bf16x8 __attribute__((ext_vector_type(8)));
typedef float f32x4 __attribute__((ext_vector_type(4)));

__device__ __forceinline__ ushort f2bf_rn(float x) {
  union { float f; uint32_t u; } c; c.f = x;
  uint32_t r = c.u + 0x7fffu + ((c.u >> 16) & 1u);
  return (ushort)(r >> 16);
}
__device__ __forceinline__ float bf2f(ushort h) {
  union { uint32_t u; float f; } c; c.u = ((uint32_t)h) << 16; return c.f;
}

// XOR-swizzled LDS index (ushort units) for 128B rows (64 bf16).
// byte ^= (row&7)<<4 spreads 16B column slots across banks (G4 pattern).
__device__ __forceinline__ int swz_idx(int row, int byte_in_row) {
  return ((row * 128 + byte_in_row) ^ ((row & 7) << 4)) >> 1;
}

// ---------------------------------------------------------------------------
// Split-bf16 (3x MFMA) GEMM, N=256 fixed: C[M,256] = A[M,K] @ B[K,256] + bias
// A fp32 row-major, converted hi/lo bf16 in-kernel, staged in LDS.
// B pre-split+transposed (BT bf16 [256][K]) staged in LDS per K-step.
// Full-N tile => A read from HBM exactly once. TM rows/block, 4 waves,
// wave w owns cols [64w,64w+64), all TM rows. BK=64.
// Register prefetch: next K-tile loads issued before MFMA phase.
// Epilogue staged through LDS for full-cache-line C stores.
// ---------------------------------------------------------------------------
template<int TM>
__global__ __launch_bounds__(256, 2) void gemm_split3_n256(
    const float* __restrict__ A,
    const ushort* __restrict__ BT_hi, const ushort* __restrict__ BT_lo,
    const float* __restrict__ bias, float* __restrict__ C,
    int M, int K)
{
  constexpr int MT = TM / 16;       // 16-row fragment groups per wave
  constexpr int AREG = TM / 16;     // float4 A-loads per thread per K-step
  __shared__ ushort smem[TM * 64 * 2 + 256 * 64 * 2];
  ushort* Ah = smem;
  ushort* Al = Ah + TM * 64;
  ushort* Bh = Al + TM * 64;
  ushort* Bl = Bh + 256 * 64;
  float* ctile = (float*)smem;      // epilogue reuse, row stride 260 floats

  const int tid  = threadIdx.x;
  const int lane = tid & 63, wave = tid >> 6;
  const int wn   = wave * 64;
  const int lrow = lane & 15, lgrp = lane >> 4;
  const long brow = (long)blockIdx.x * TM;

  f32x4 acc[MT][4] = {};

  float4 areg[AREG];
  uint4  bhreg[8], blreg[8];

  // ---- prologue: load K-tile 0 into regs ----
#pragma unroll
  for (int i = 0; i < AREG; ++i) {
    const int idx = i * 256 + tid, r = idx >> 4, c4 = (idx & 15) << 2;
    areg[i] = *(const float4*)&A[(size_t)(brow + r) * K + c4];
  }
#pragma unroll
  for (int i = 0; i < 8; ++i) {
    const int idx = i * 256 + tid, r = idx >> 3, c8 = (idx & 7) << 3;
    bhreg[i] = *(const uint4*)&BT_hi[(size_t)r * K + c8];
    blreg[i] = *(const uint4*)&BT_lo[(size_t)r * K + c8];
  }

  for (int k0 = 0; k0 < K; k0 += 64) {
    __syncthreads();   // previous MFMA phase's LDS reads complete

    // ---- convert + LDS write from prefetch regs ----
#pragma unroll
    for (int i = 0; i < AREG; ++i) {
      const int idx = i * 256 + tid, r = idx >> 4, c4 = (idx & 15) << 2;
      const float v[4] = {areg[i].x, areg[i].y, areg[i].z, areg[i].w};
      ushort hi[4], lo[4];
#pragma unroll
      for (int j = 0; j < 4; ++j) {
        hi[j] = f2bf_rn(v[j]);
        lo[j] = f2bf_rn(v[j] - bf2f(hi[j]));
      }
      const int si = swz_idx(r, c4 * 2);
      *(ushort4*)&Ah[si] = make_ushort4(hi[0], hi[1], hi[2], hi[3]);
      *(ushort4*)&Al[si] = make_ushort4(lo[0], lo[1], lo[2], lo[3]);
    }
#pragma unroll
    for (int i = 0; i < 8; ++i) {
      const int idx = i * 256 + tid, r = idx >> 3, c8 = (idx & 7) << 3;
      const int si = swz_idx(r, c8 * 2);
      *(uint4*)&Bh[si] = bhreg[i];
      *(uint4*)&Bl[si] = blreg[i];
    }

    __syncthreads();

    // ---- prefetch next K-tile (flies during MFMA phase) ----
    const int kn = k0 + 64;
    if (kn < K) {
#pragma unroll
      for (int i = 0; i < AREG; ++i) {
        const int idx = i * 256 + tid, r = idx >> 4, c4 = (idx & 15) << 2;
        areg[i] = *(const float4*)&A[(size_t)(brow + r) * K + kn + c4];
      }
#pragma unroll
      for (int i = 0; i < 8; ++i) {
        const int idx = i * 256 + tid, r = idx >> 3, c8 = (idx & 7) << 3;
        bhreg[i] = *(const uint4*)&BT_hi[(size_t)r * K + kn + c8];
        blreg[i] = *(const uint4*)&BT_lo[(size_t)r * K + kn + c8];
      }
    }

    // ---- MFMA phase ----
#pragma unroll
    for (int s = 0; s < 2; ++s) {
      bf16x8 ah[MT], al[MT], bh[4], bl[4];
#pragma unroll
      for (int t = 0; t < MT; ++t) {
        const int ai = swz_idx(t * 16 + lrow, s * 64 + lgrp * 16);
        ah[t] = *(const bf16x8*)&Ah[ai];
        al[t] = *(const bf16x8*)&Al[ai];
      }
#pragma unroll
      for (int t = 0; t < 4; ++t) {
        const int bi = swz_idx(wn + t * 16 + lrow, s * 64 + lgrp * 16);
        bh[t] = *(const bf16x8*)&Bh[bi];
        bl[t] = *(const bf16x8*)&Bl[bi];
      }
#pragma unroll
      for (int mt = 0; mt < MT; ++mt)
#pragma unroll
        for (int nt = 0; nt < 4; ++nt) {
          acc[mt][nt] = __builtin_amdgcn_mfma_f32_16x16x32_bf16(ah[mt], bh[nt], acc[mt][nt], 0, 0, 0);
          acc[mt][nt] = __builtin_amdgcn_mfma_f32_16x16x32_bf16(ah[mt], bl[nt], acc[mt][nt], 0, 0, 0);
          acc[mt][nt] = __builtin_amdgcn_mfma_f32_16x16x32_bf16(al[mt], bh[nt], acc[mt][nt], 0, 0, 0);
        }
    }
  }

  // ---- epilogue: acc -> LDS (stride 260) -> coalesced full-line stores ----
  __syncthreads();   // staging LDS dead
#pragma unroll
  for (int nt = 0; nt < 4; ++nt) {
    const int col = wn + nt * 16 + lrow;
    const float bb = bias[col];
#pragma unroll
    for (int mt = 0; mt < MT; ++mt) {
      const int r0 = mt * 16 + lgrp * 4;
      const f32x4 v = acc[mt][nt];
#pragma unroll
      for (int j = 0; j < 4; ++j)
        ctile[(r0 + j) * 260 + col] = v[j] + bb;
    }
  }
  __syncthreads();
#pragma unroll
  for (int i = 0; i < TM / 4; ++i) {   // TM*64 float4s / 256 threads
    const int idx = i * 256 + tid, r = idx >> 6, c4 = (idx & 63) << 2;
    *(float4*)&C[(size_t)(brow + r) * 256 + c4] = *(const float4*)&ctile[r * 260 + c4];
  }
}

// ---------------------------------------------------------------------------
// Weight prep: W fp32 [256][256] -> WT_hi/WT_lo bf16 [n][k] (transposed+split)
// ---------------------------------------------------------------------------
__global__ __launch_bounds__(256) void prep_wt(
    const float* __restrict__ W, ushort* __restrict__ WT_hi, ushort* __restrict__ WT_lo)
{
  const int n = blockIdx.x;
  const int k = threadIdx.x;
  const float w = W[k * 256 + n];
  const ushort hi = f2bf_rn(w);
  const ushort lo = f2bf_rn(w - bf2f(hi));
  WT_hi[n * 256 + k] = hi;
  WT_lo[n * 256 + k] = lo;
}

// ---------------------------------------------------------------------------
// Offsets + attention-logits projection (unchanged).
// ---------------------------------------------------------------------------
__global__ __launch_bounds__(128) void proj_kernel(
    const float* __restrict__ query,
    const float* __restrict__ W_off, const float* __restrict__ b_off,
    const float* __restrict__ W_attn, const float* __restrict__ b_attn,
    float* __restrict__ offs, float* __restrict__ logits)
{
  __shared__ float q_lds[8][256];
  const int row0 = blockIdx.x * 8;
  const int tid  = threadIdx.x;

  for (int i = tid; i < 512; i += 128) {
    const int r  = i >> 6;
    const int c4 = (i & 63) << 2;
    *(float4*)&q_lds[r][c4] = *(const float4*)&query[(size_t)(row0 + r) * 256 + c4];
  }
  __syncthreads();
  if (tid >= 96) return;

  float acc[8] = {};
  if (tid < 64) {
    for (int k4 = 0; k4 < 256; k4 += 4) {
      const float w0 = W_off[(k4 + 0) * 64 + tid];
      const float w1 = W_off[(k4 + 1) * 64 + tid];
      const float w2 = W_off[(k4 + 2) * 64 + tid];
      const float w3 = W_off[(k4 + 3) * 64 + tid];
#pragma unroll
      for (int r = 0; r < 8; ++r) {
        float4 q4 = *(const float4*)&q_lds[r][k4];
        acc[r] += q4.x * w0 + q4.y * w1 + q4.z * w2 + q4.w * w3;
      }
    }
    const float bb = b_off[tid];
#pragma unroll
    for (int r = 0; r < 8; ++r)
      offs[(size_t)(row0 + r) * 64 + tid] = acc[r] + bb;
  } else {
    const int j = tid - 64;
    for (int k4 = 0; k4 < 256; k4 += 4) {
      const float w0 = W_attn[(k4 + 0) * 32 + j];
      const float w1 = W_attn[(k4 + 1) * 32 + j];
      const float w2 = W_attn[(k4 + 2) * 32 + j];
      const float w3 = W_attn[(k4 + 3) * 32 + j];
#pragma unroll
      for (int r = 0; r < 8; ++r) {
        float4 q4 = *(const float4*)&q_lds[r][k4];
        acc[r] += q4.x * w0 + q4.y * w1 + q4.z * w2 + q4.w * w3;
      }
    }
    const float bb = b_attn[j];
#pragma unroll
    for (int r = 0; r < 8; ++r)
      logits[(size_t)(row0 + r) * 32 + j] = acc[r] + bb;
  }
}

// ---------------------------------------------------------------------------
// Softmax + bilinear sampling, wave-per-query, float4 per lane.
// Block = 4 waves = 4 queries. Lane owns channels [4*lane, 4*lane+4),
// head = lane>>3; each head's 8 lanes fetch contiguous 128B corner segments.
// ---------------------------------------------------------------------------
__global__ __launch_bounds__(256, 8) void sample_kernel(
    const float* __restrict__ refp,    // [BQ,2]
    const float* __restrict__ offs,    // [BQ,64]  (h*8 + p*2 + c)
    const float* __restrict__ logits,  // [BQ,32]  (h*4 + p)
    const float* __restrict__ values,  // [B,HW,256]
    float* __restrict__ mid,           // [BQ,256]
    const int* __restrict__ hptr, const int* __restrict__ wptr,
    int Q, int HW)
{
  const int lane = threadIdx.x & 63;
  const int bq   = blockIdx.x * 4 + (threadIdx.x >> 6);
  const int b    = bq / Q;
  const int W_   = *wptr;
  const int H_   = *hptr;
  const int h    = lane >> 3;

  // softmax over 4 points for this head (redundant across the 8 lanes)
  const float l0 = logits[(size_t)bq * 32 + h * 4 + 0];
  const float l1 = logits[(size_t)bq * 32 + h * 4 + 1];
  const float l2 = logits[(size_t)bq * 32 + h * 4 + 2];
  const float l3 = logits[(size_t)bq * 32 + h * 4 + 3];
  const float m  = fmaxf(fmaxf(l0, l1), fmaxf(l2, l3));
  const float e0 = __expf(l0 - m), e1 = __expf(l1 - m);
  const float e2 = __expf(l2 - m), e3 = __expf(l3 - m);
  const float inv = 1.0f / (e0 + e1 + e2 + e3);
  float wt[4] = {e0 * inv, e1 * inv, e2 * inv, e3 * inv};

  const float rx = refp[(size_t)bq * 2 + 0];
  const float ry = refp[(size_t)bq * 2 + 1];
  const float* vb = values + (size_t)b * HW * 256;
  const int ch = lane * 4;

  f32x4 acc = {0.f, 0.f, 0.f, 0.f};
#pragma unroll
  for (int p = 0; p < NPOINTS; ++p) {
    float lx = rx + offs[(size_t)bq * 64 + h * 8 + p * 2 + 0];
    float ly = ry + offs[(size_t)bq * 64 + h * 8 + p * 2 + 1];
    lx = fminf(fmaxf(lx, 0.0f), 1.0f);
    ly = fminf(fmaxf(ly, 0.0f), 1.0f);
    const float sx = lx * (float)(W_ - 1);
    const float sy = ly * (float)(H_ - 1);
    int x0 = (int)floorf(sx);
    int y0 = (int)floorf(sy);
    x0 = min(max(x0, 0), W_ - 1);
    y0 = min(max(y0, 0), H_ - 1);
    const int x1 = min(x0 + 1, W_ - 1);
    const int y1 = min(y0 + 1, H_ - 1);
    const float wx1 = sx - (float)x0, wx0 = 1.0f - wx1;
    const float wy1 = sy - (float)y0, wy0 = 1.0f - wy1;

    const f32x4 g00 = *(const f32x4*)&vb[(size_t)(y0 * W_ + x0) * 256 + ch];
    const f32x4 g10 = *(const f32x4*)&vb[(size_t)(y0 * W_ + x1) * 256 + ch];
    const f32x4 g01 = *(const f32x4*)&vb[(size_t)(y1 * W_ + x0) * 256 + ch];
    const f32x4 g11 = *(const f32x4*)&vb[(size_t)(y1 * W_ + x1) * 256 + ch];

    const float w00 = wx0 * wy0, w10 = wx1 * wy0, w01 = wx0 * wy1, w11 = wx1 * wy1;
    const float wp = wt[p];
#pragma unroll
    for (int j = 0; j < 4; ++j)
      acc[j] += wp * (g00[j] * w00 + g01[j] * w01 + g10[j] * w10 + g11[j] * w11);
  }
  *(f32x4*)&mid[(size_t)bq * 256 + ch] = acc;
}

// ---------------------------------------------------------------------------
extern "C" void kernel_launch(void* const* d_in, const int* in_sizes, int n_in,
                              void* d_out, int out_size, void* d_ws, size_t ws_size,
                              hipStream_t stream)
{
  const float* query   = (const float*)d_in[0];
  const float* refp    = (const float*)d_in[1];
  const float* input_f = (const float*)d_in[2];
  const int*   hptr    = (const int*)d_in[3];
  const int*   wptr    = (const int*)d_in[4];
  const float* W_off   = (const float*)d_in[5];
  const float* b_off   = (const float*)d_in[6];
  const float* W_attn  = (const float*)d_in[7];
  const float* b_attn  = (const float*)d_in[8];
  const float* W_val   = (const float*)d_in[9];
  const float* b_val   = (const float*)d_in[10];
  const float* W_out   = (const float*)d_in[11];
  const float* b_out   = (const float*)d_in[12];
  float* out = (float*)d_out;

  const int D   = 256;
  const int BQ  = in_sizes[0] / D;   // 16384
  const int B   = 8;
  const int Q   = BQ / B;            // 2048
  const int BHW = in_sizes[2] / D;   // 80000
  const int HW  = BHW / B;           // 10000

  char* ws = (char*)d_ws;
  float* values = (float*)ws;                                   // 81.92 MB
  size_t o = (size_t)BHW * D * sizeof(float);
  float* offsb  = (float*)(ws + o);  o += (size_t)BQ * 64 * sizeof(float);  // 4.19 MB
  float* logitb = (float*)(ws + o);  o += (size_t)BQ * 32 * sizeof(float);  // 2.10 MB
  float* mid    = (float*)(ws + o);                             // 16.78 MB

  // Split-weight overlays on dead regions:
  //  - WvT (512 KB) at head of `mid` (dead until sample writes mid; WvT dead after gemm1)
  //  - WoT (512 KB) at head of `offs` (offs dead after sample; WoT written after sample)
  ushort* WvT_hi = (ushort*)mid;
  ushort* WvT_lo = WvT_hi + 256 * 256;
  ushort* WoT_hi = (ushort*)offsb;
  ushort* WoT_lo = WoT_hi + 256 * 256;

  // 1. values = input_flatten @ W_val + b_val
  prep_wt<<<256, 256, 0, stream>>>(W_val, WvT_hi, WvT_lo);
  gemm_split3_n256<64><<<BHW / 64, 256, 0, stream>>>(
      input_f, WvT_hi, WvT_lo, b_val, values, BHW, D);

  // 2. offsets + attention logits
  proj_kernel<<<BQ / 8, 128, 0, stream>>>(
      query, W_off, b_off, W_attn, b_attn, offsb, logitb);

  // 3. softmax + bilinear sampling -> mid
  sample_kernel<<<BQ / 4, 256, 0, stream>>>(
      refp, offsb, logitb, values, mid, hptr, wptr, Q, HW);

  // 4. out = mid @ W_out + b_out
  prep_wt<<<256, 256, 0, stream>>>(W_out, WoT_hi, WoT_lo);
  gemm_split3_n256<32><<<BQ / 32, 256, 0, stream>>>(
      mid, WoT_hi, WoT_lo, b_out, out, BQ, D);
}

// Round 5
// 117.563 us; speedup vs baseline: 2.4925x; 2.0313x over previous
//
#include <hip/hip_runtime.h>
#include <hip/hip_bf16.h>
#include <cstdint>

#define NHEADS 8
#define NPOINTS 4

typedef __bf16 bf16x8 __attribute__((ext_vector_type(8)));
typedef float f32x4 __attribute__((ext_vector_type(4)));

#define AS1 __attribute__((address_space(1)))
#define AS3 __attribute__((address_space(3)))

__device__ __forceinline__ ushort f2bf_rn(float x) {
  union { float f; uint32_t u; } c; c.f = x;
  uint32_t r = c.u + 0x7fffu + ((c.u >> 16) & 1u);
  return (ushort)(r >> 16);
}
__device__ __forceinline__ float bf2f(ushort h) {
  union { uint32_t u; float f; } c; c.u = ((uint32_t)h) << 16; return c.f;
}
__device__ __forceinline__ uint pack2(ushort a, ushort b) {
  return (uint)a | ((uint)b << 16);
}

// LDS rows are 128 B = 8 granules of 16 B: granules 0-3 = hi (32 bf16),
// granules 4-7 = lo. Granule index is XOR-swizzled by (row&7) — verified
// conflict-free read pattern (SQ_LDS_BANK_CONFLICT==0 in rounds 3/4).
// Returns ushort index of granule g0 of `row`.
__device__ __forceinline__ int gidx(int row, int g0) {
  return row * 64 + ((g0 ^ (row & 7)) << 3);
}

// ---------------------------------------------------------------------------
// Split-bf16 (3x MFMA) GEMM, N=256: C[M,256] = A[M,K] @ B[K,256] + bias.
// A fp32 row-major -> hi/lo bf16 in LDS (packed 128B rows), reg-prefetched.
// B staged per K-step via global_load_lds from PRE-SWIZZLED Bprep (see
// prep_wt): linear LDS dest + pre-swizzled source + swizzled read.
// BK=32, NT=K/32 steps. 4 waves; wave w owns cols [64w,64w+64).
// LDS = TM*128 B (A) + 32 KB (B)  => 40 KB @ TM=64.
// ---------------------------------------------------------------------------
template<int TM>
__global__ __launch_bounds__(256, 3) void gemm_split3_n256(
    const float* __restrict__ A,
    const ushort* __restrict__ Bprep,   // [K/32][16384] pre-swizzled ushorts
    const float* __restrict__ bias, float* __restrict__ C,
    int M, int K)
{
  constexpr int MT = TM / 16;
  __shared__ ushort smem[TM * 64 + 16384];   // A region | B region
  const int tid  = threadIdx.x;
  const int lane = tid & 63, wave = tid >> 6;
  const int wn   = wave * 64;
  const int lrow = lane & 15, lgrp = lane >> 4;
  const long brow = (long)blockIdx.x * TM;
  const int NT = K >> 5;
  constexpr int BOFF = TM * 64;              // B region base (ushorts)

  f32x4 acc[MT][4] = {};

  // ---- issue B chunk 0 (async -> LDS) ----
#pragma unroll
  for (int j = 0; j < 8; ++j) {
    const ushort* src = Bprep + (size_t)wave * 512 + (size_t)j * 2048 + (size_t)lane * 8;
    __builtin_amdgcn_global_load_lds((const AS1 void*)src,
                                     (AS3 void*)&smem[BOFF + wave * 512 + j * 2048],
                                     16, 0, 0);
  }

  // ---- A stage-thread mapping + prologue A loads (chunk 0) ----
  float4 areg0, areg1;                 // TM==64: 8 floats; TM==32: areg0 only
  int arow, agq;                       // agq: granule (TM=64) or half-granule (TM=32)
  if constexpr (TM == 64) {
    arow = tid >> 2; agq = tid & 3;
    const float* ap = &A[(size_t)(brow + arow) * K + agq * 8];
    areg0 = *(const float4*)ap;
    areg1 = *(const float4*)(ap + 4);
  } else {
    arow = tid >> 3; agq = tid & 7;
    areg0 = *(const float4*)&A[(size_t)(brow + arow) * K + agq * 4];
  }

  for (int t = 0; t < NT; ++t) {
    __syncthreads();   // prev MFMA done with LDS (also drains prefetches)

    // ---- issue B chunk t (t>0; chunk 0 pre-issued) ----
    if (t > 0) {
#pragma unroll
      for (int j = 0; j < 8; ++j) {
        const ushort* src = Bprep + (size_t)t * 16384 + (size_t)wave * 512
                          + (size_t)j * 2048 + (size_t)lane * 8;
        __builtin_amdgcn_global_load_lds((const AS1 void*)src,
                                         (AS3 void*)&smem[BOFF + wave * 512 + j * 2048],
                                         16, 0, 0);
      }
    }

    // ---- convert + write A chunk t from prefetch regs ----
    if constexpr (TM == 64) {
      const float v[8] = {areg0.x, areg0.y, areg0.z, areg0.w,
                          areg1.x, areg1.y, areg1.z, areg1.w};
      ushort h[8], l[8];
#pragma unroll
      for (int j = 0; j < 8; ++j) {
        h[j] = f2bf_rn(v[j]);
        l[j] = f2bf_rn(v[j] - bf2f(h[j]));
      }
      uint4 hv = {pack2(h[0],h[1]), pack2(h[2],h[3]), pack2(h[4],h[5]), pack2(h[6],h[7])};
      uint4 lv = {pack2(l[0],l[1]), pack2(l[2],l[3]), pack2(l[4],l[5]), pack2(l[6],l[7])};
      *(uint4*)&smem[gidx(arow, agq)]     = hv;
      *(uint4*)&smem[gidx(arow, agq + 4)] = lv;
    } else {
      const float v[4] = {areg0.x, areg0.y, areg0.z, areg0.w};
      ushort h[4], l[4];
#pragma unroll
      for (int j = 0; j < 4; ++j) {
        h[j] = f2bf_rn(v[j]);
        l[j] = f2bf_rn(v[j] - bf2f(h[j]));
      }
      const int g = agq >> 1, half = (agq & 1) * 4;
      uint2 hv = {pack2(h[0],h[1]), pack2(h[2],h[3])};
      uint2 lv = {pack2(l[0],l[1]), pack2(l[2],l[3])};
      *(uint2*)&smem[gidx(arow, g)     + half] = hv;
      *(uint2*)&smem[gidx(arow, g + 4) + half] = lv;
    }

    __syncthreads();   // drains B global_load_lds (vm) + A ds_writes (lgkm)

    // ---- prefetch A chunk t+1 (flies under MFMA) ----
    if (t + 1 < NT) {
      if constexpr (TM == 64) {
        const float* ap = &A[(size_t)(brow + arow) * K + (t + 1) * 32 + agq * 8];
        areg0 = *(const float4*)ap;
        areg1 = *(const float4*)(ap + 4);
      } else {
        areg0 = *(const float4*)&A[(size_t)(brow + arow) * K + (t + 1) * 32 + agq * 4];
      }
    }

    // ---- MFMA over chunk t ----
    bf16x8 ah[MT], al[MT];
#pragma unroll
    for (int mt = 0; mt < MT; ++mt) {
      const int r = mt * 16 + lrow;
      ah[mt] = *(const bf16x8*)&smem[gidx(r, lgrp)];
      al[mt] = *(const bf16x8*)&smem[gidx(r, lgrp + 4)];
    }
#pragma unroll
    for (int nt = 0; nt < 4; ++nt) {
      const int r = wn + nt * 16 + lrow;
      const bf16x8 bh = *(const bf16x8*)&smem[BOFF + gidx(r, lgrp)];
      const bf16x8 bl = *(const bf16x8*)&smem[BOFF + gidx(r, lgrp + 4)];
#pragma unroll
      for (int mt = 0; mt < MT; ++mt) {
        acc[mt][nt] = __builtin_amdgcn_mfma_f32_16x16x32_bf16(ah[mt], bh, acc[mt][nt], 0, 0, 0);
        acc[mt][nt] = __builtin_amdgcn_mfma_f32_16x16x32_bf16(ah[mt], bl, acc[mt][nt], 0, 0, 0);
        acc[mt][nt] = __builtin_amdgcn_mfma_f32_16x16x32_bf16(al[mt], bh, acc[mt][nt], 0, 0, 0);
      }
    }
  }

  // ---- epilogue: 32-row passes through LDS, full-line coalesced stores ----
  float bb[4];
#pragma unroll
  for (int nt = 0; nt < 4; ++nt) bb[nt] = bias[wn + nt * 16 + lrow];
  float* ctile = (float*)smem;               // 32 x 260 floats = 33.3 KB
#pragma unroll
  for (int h = 0; h < TM / 32; ++h) {
    __syncthreads();
#pragma unroll
    for (int m2 = 0; m2 < 2; ++m2) {
      const int mt = h * 2 + m2;
      const int lr0 = m2 * 16 + lgrp * 4;
#pragma unroll
      for (int nt = 0; nt < 4; ++nt) {
        const int col = wn + nt * 16 + lrow;
#pragma unroll
        for (int j = 0; j < 4; ++j)
          ctile[(lr0 + j) * 260 + col] = acc[mt][nt][j] + bb[nt];
      }
    }
    __syncthreads();
#pragma unroll
    for (int i = 0; i < 8; ++i) {
      const int idx = i * 256 + tid, r = idx >> 6, c4 = (idx & 63) << 2;
      *(float4*)&C[(size_t)(brow + h * 32 + r) * 256 + c4] = *(const float4*)&ctile[r * 260 + c4];
    }
  }
}

// ---------------------------------------------------------------------------
// Weight prep: W fp32 [256][256] -> Bprep (pre-swizzled, K-step-tiled).
// Chunk t (16384 ushorts) is the exact LDS image for K-step t: row r holds
// [hi granules 0-3 | lo granules 4-7] of W[32t..32t+32][r], granule-XOR-
// swizzled by (r&7). global_load_lds copies it linearly; reads un-swizzle.
// ---------------------------------------------------------------------------
__global__ __launch_bounds__(256) void prep_wt(
    const float* __restrict__ W, ushort* __restrict__ Bprep)
{
  const int pg = blockIdx.x * 256 + threadIdx.x;  // 0..131071
  const int t = pg >> 14;
  const int p = pg & 16383;
  const int r = p >> 6;
  const int q = p & 63;
  const int g0 = (q >> 3) ^ (r & 7);              // unswizzled granule
  const int q0 = g0 * 8 + (q & 7);                // unswizzled ushort in row
  const int kk = q0 & 31;
  const float w = W[(size_t)(t * 32 + kk) * 256 + r];
  const ushort hi = f2bf_rn(w);
  Bprep[pg] = (q0 < 32) ? hi : f2bf_rn(w - bf2f(hi));
}

// ---------------------------------------------------------------------------
// Offsets + attention-logits projection (unchanged).
// ---------------------------------------------------------------------------
__global__ __launch_bounds__(128) void proj_kernel(
    const float* __restrict__ query,
    const float* __restrict__ W_off, const float* __restrict__ b_off,
    const float* __restrict__ W_attn, const float* __restrict__ b_attn,
    float* __restrict__ offs, float* __restrict__ logits)
{
  __shared__ float q_lds[8][256];
  const int row0 = blockIdx.x * 8;
  const int tid  = threadIdx.x;

  for (int i = tid; i < 512; i += 128) {
    const int r  = i >> 6;
    const int c4 = (i & 63) << 2;
    *(float4*)&q_lds[r][c4] = *(const float4*)&query[(size_t)(row0 + r) * 256 + c4];
  }
  __syncthreads();
  if (tid >= 96) return;

  float acc[8] = {};
  if (tid < 64) {
    for (int k4 = 0; k4 < 256; k4 += 4) {
      const float w0 = W_off[(k4 + 0) * 64 + tid];
      const float w1 = W_off[(k4 + 1) * 64 + tid];
      const float w2 = W_off[(k4 + 2) * 64 + tid];
      const float w3 = W_off[(k4 + 3) * 64 + tid];
#pragma unroll
      for (int r = 0; r < 8; ++r) {
        float4 q4 = *(const float4*)&q_lds[r][k4];
        acc[r] += q4.x * w0 + q4.y * w1 + q4.z * w2 + q4.w * w3;
      }
    }
    const float bb = b_off[tid];
#pragma unroll
    for (int r = 0; r < 8; ++r)
      offs[(size_t)(row0 + r) * 64 + tid] = acc[r] + bb;
  } else {
    const int j = tid - 64;
    for (int k4 = 0; k4 < 256; k4 += 4) {
      const float w0 = W_attn[(k4 + 0) * 32 + j];
      const float w1 = W_attn[(k4 + 1) * 32 + j];
      const float w2 = W_attn[(k4 + 2) * 32 + j];
      const float w3 = W_attn[(k4 + 3) * 32 + j];
#pragma unroll
      for (int r = 0; r < 8; ++r) {
        float4 q4 = *(const float4*)&q_lds[r][k4];
        acc[r] += q4.x * w0 + q4.y * w1 + q4.z * w2 + q4.w * w3;
      }
    }
    const float bb = b_attn[j];
#pragma unroll
    for (int r = 0; r < 8; ++r)
      logits[(size_t)(row0 + r) * 32 + j] = acc[r] + bb;
  }
}

// ---------------------------------------------------------------------------
// Softmax + bilinear sampling, wave-per-query, float4 per lane (unchanged).
// ---------------------------------------------------------------------------
__global__ __launch_bounds__(256, 8) void sample_kernel(
    const float* __restrict__ refp,    // [BQ,2]
    const float* __restrict__ offs,    // [BQ,64]  (h*8 + p*2 + c)
    const float* __restrict__ logits,  // [BQ,32]  (h*4 + p)
    const float* __restrict__ values,  // [B,HW,256]
    float* __restrict__ mid,           // [BQ,256]
    const int* __restrict__ hptr, const int* __restrict__ wptr,
    int Q, int HW)
{
  const int lane = threadIdx.x & 63;
  const int bq   = blockIdx.x * 4 + (threadIdx.x >> 6);
  const int b    = bq / Q;
  const int W_   = *wptr;
  const int H_   = *hptr;
  const int h    = lane >> 3;

  const float l0 = logits[(size_t)bq * 32 + h * 4 + 0];
  const float l1 = logits[(size_t)bq * 32 + h * 4 + 1];
  const float l2 = logits[(size_t)bq * 32 + h * 4 + 2];
  const float l3 = logits[(size_t)bq * 32 + h * 4 + 3];
  const float m  = fmaxf(fmaxf(l0, l1), fmaxf(l2, l3));
  const float e0 = __expf(l0 - m), e1 = __expf(l1 - m);
  const float e2 = __expf(l2 - m), e3 = __expf(l3 - m);
  const float inv = 1.0f / (e0 + e1 + e2 + e3);
  float wt[4] = {e0 * inv, e1 * inv, e2 * inv, e3 * inv};

  const float rx = refp[(size_t)bq * 2 + 0];
  const float ry = refp[(size_t)bq * 2 + 1];
  const float* vb = values + (size_t)b * HW * 256;
  const int ch = lane * 4;

  f32x4 acc = {0.f, 0.f, 0.f, 0.f};
#pragma unroll
  for (int p = 0; p < NPOINTS; ++p) {
    float lx = rx + offs[(size_t)bq * 64 + h * 8 + p * 2 + 0];
    float ly = ry + offs[(size_t)bq * 64 + h * 8 + p * 2 + 1];
    lx = fminf(fmaxf(lx, 0.0f), 1.0f);
    ly = fminf(fmaxf(ly, 0.0f), 1.0f);
    const float sx = lx * (float)(W_ - 1);
    const float sy = ly * (float)(H_ - 1);
    int x0 = (int)floorf(sx);
    int y0 = (int)floorf(sy);
    x0 = min(max(x0, 0), W_ - 1);
    y0 = min(max(y0, 0), H_ - 1);
    const int x1 = min(x0 + 1, W_ - 1);
    const int y1 = min(y0 + 1, H_ - 1);
    const float wx1 = sx - (float)x0, wx0 = 1.0f - wx1;
    const float wy1 = sy - (float)y0, wy0 = 1.0f - wy1;

    const f32x4 g00 = *(const f32x4*)&vb[(size_t)(y0 * W_ + x0) * 256 + ch];
    const f32x4 g10 = *(const f32x4*)&vb[(size_t)(y0 * W_ + x1) * 256 + ch];
    const f32x4 g01 = *(const f32x4*)&vb[(size_t)(y1 * W_ + x0) * 256 + ch];
    const f32x4 g11 = *(const f32x4*)&vb[(size_t)(y1 * W_ + x1) * 256 + ch];

    const float w00 = wx0 * wy0, w10 = wx1 * wy0, w01 = wx0 * wy1, w11 = wx1 * wy1;
    const float wp = wt[p];
#pragma unroll
    for (int j = 0; j < 4; ++j)
      acc[j] += wp * (g00[j] * w00 + g01[j] * w01 + g10[j] * w10 + g11[j] * w11);
  }
  *(f32x4*)&mid[(size_t)bq * 256 + ch] = acc;
}

// ---------------------------------------------------------------------------
extern "C" void kernel_launch(void* const* d_in, const int* in_sizes, int n_in,
                              void* d_out, int out_size, void* d_ws, size_t ws_size,
                              hipStream_t stream)
{
  const float* query   = (const float*)d_in[0];
  const float* refp    = (const float*)d_in[1];
  const float* input_f = (const float*)d_in[2];
  const int*   hptr    = (const int*)d_in[3];
  const int*   wptr    = (const int*)d_in[4];
  const float* W_off   = (const float*)d_in[5];
  const float* b_off   = (const float*)d_in[6];
  const float* W_attn  = (const float*)d_in[7];
  const float* b_attn  = (const float*)d_in[8];
  const float* W_val   = (const float*)d_in[9];
  const float* b_val   = (const float*)d_in[10];
  const float* W_out   = (const float*)d_in[11];
  const float* b_out   = (const float*)d_in[12];
  float* out = (float*)d_out;

  const int D   = 256;
  const int BQ  = in_sizes[0] / D;   // 16384
  const int B   = 8;
  const int Q   = BQ / B;            // 2048
  const int BHW = in_sizes[2] / D;   // 80000
  const int HW  = BHW / B;           // 10000

  char* ws = (char*)d_ws;
  float* values = (float*)ws;                                   // 81.92 MB
  size_t o = (size_t)BHW * D * sizeof(float);
  float* offsb  = (float*)(ws + o);  o += (size_t)BQ * 64 * sizeof(float);  // 4.19 MB
  float* logitb = (float*)(ws + o);  o += (size_t)BQ * 32 * sizeof(float);  // 2.10 MB
  float* mid    = (float*)(ws + o);                             // 16.78 MB

  // Pre-swizzled weight overlays on dead regions (256 KB each):
  //  - Bprep_val at head of `mid` (dead until sample writes mid)
  //  - Bprep_out at head of `offsb` (offs dead after sample)
  ushort* Bprep_val = (ushort*)mid;
  ushort* Bprep_out = (ushort*)offsb;

  // 1. values = input_flatten @ W_val + b_val
  prep_wt<<<512, 256, 0, stream>>>(W_val, Bprep_val);
  gemm_split3_n256<64><<<BHW / 64, 256, 0, stream>>>(
      input_f, Bprep_val, b_val, values, BHW, D);

  // 2. offsets + attention logits
  proj_kernel<<<BQ / 8, 128, 0, stream>>>(
      query, W_off, b_off, W_attn, b_attn, offsb, logitb);

  // 3. softmax + bilinear sampling -> mid
  sample_kernel<<<BQ / 4, 256, 0, stream>>>(
      refp, offsb, logitb, values, mid, hptr, wptr, Q, HW);

  // 4. out = mid @ W_out + b_out
  prep_wt<<<512, 256, 0, stream>>>(W_out, Bprep_out);
  gemm_split3_n256<32><<<BQ / 32, 256, 0, stream>>>(
      mid, Bprep_out, b_out, out, BQ, D);
}